// Round 2
// 110.671 us; speedup vs baseline: 1.0073x; 1.0073x over previous
//
#include <hip/hip_runtime.h>
#include <math.h>

#define T_LEN   4000
#define CHUNK   256            // 64 lanes * 4 elements
#define NCHUNK  16             // ceil(4000/256); last chunk: lanes 0..39 valid

// clang-native vector for nontemporal builtin (HIP float4 is a struct type
// the builtin rejects)
typedef float f32x4 __attribute__((ext_vector_type(4)));

__device__ __forceinline__ float pcen_elem(float xv, float s) {
    const float ALPHA = 0.98f;
    const float DELTA = 2.0f;
    const float SQRT_DELTA = 1.4142135623730951f;
    const float EPS = 1e-6f;
    // native ops: v_log_f32 (base2), v_exp_f32 (base2), v_sqrt_f32 (~1 ulp)
    float p = __builtin_amdgcn_exp2f(-ALPHA * __builtin_amdgcn_logf(s + EPS));
    return __builtin_amdgcn_sqrtf(fmaf(xv, p, DELTA)) - SQRT_DELTA;
}

// One wave owns one full 4000-sample row: no lookback re-read, no divergent
// prologue, exact recurrence. 4096 rows -> 4096 waves -> 1024 blocks of 4
// waves -> exactly 4 blocks/CU, all co-resident (launch_bounds(256,4)):
// zero residency-tail, vs the previous 2-wave/row split (2048 blocks, 6
// resident of 8 per CU -> 1/3-occupancy tail round).
__global__ __launch_bounds__(256, 4) void pcen_kernel(const float* __restrict__ x,
                                                      float* __restrict__ out,
                                                      int nrows) {
    const float ALPHA = 0.98f;
    const float OMA   = 0.02f;
    // Rd = alpha^(4*d) — compile-time composed multipliers
    const float R1   = 0.92236816f;   // alpha^4
    const float R2   = 0.85076302f;   // alpha^8
    const float R4   = 0.72379773f;   // alpha^16
    const float R8   = 0.52388316f;   // alpha^32
    const float R16  = 0.27445340f;   // alpha^64
    const float R32  = 0.07532467f;   // alpha^128
    const float A256 = 0.00567380f;   // alpha^256 — per-chunk carry multiplier

    const int lane = threadIdx.x & 63;
    const int wave = threadIdx.x >> 6;
    const int row  = blockIdx.x * 4 + wave;
    if (row >= nrows) return;

    const float* __restrict__ xr   = x   + (size_t)row * T_LEN;
    float* __restrict__       orow = out + (size_t)row * T_LEN;

    // per-lane exclusive multiplier alpha^(4*lane)
    float powl = 1.0f;
    powl *= (lane & 1)  ? R1  : 1.0f;
    powl *= (lane & 2)  ? R2  : 1.0f;
    powl *= (lane & 4)  ? R4  : 1.0f;
    powl *= (lane & 8)  ? R8  : 1.0f;
    powl *= (lane & 16) ? R16 : 1.0f;
    powl *= (lane & 32) ? R32 : 1.0f;

    float s_prev = 0.0f;
#pragma unroll
    for (int c = 0; c < NCHUNK; ++c) {
        const int t0 = c * CHUNK + lane * 4;
        const bool valid = (t0 < T_LEN);     // tail chunk: lanes 0..39

        float4 vc = make_float4(0.f, 0.f, 0.f, 0.f);
        if (valid) vc = *reinterpret_cast<const float4*>(xr + t0);

        // local affine compose (b only; multiplier is constant alpha^4)
        // t==0: A=0, B=x0 (only c==0,lane==0; folds away for c>0)
        float b = (c == 0 && lane == 0) ? vc.x : OMA * vc.x;
        b = fmaf(ALPHA, b, OMA * vc.y);
        b = fmaf(ALPHA, b, OMA * vc.z);
        b = fmaf(ALPHA, b, OMA * vc.w);
        // invalid tail lanes: vc==0 -> b==0; they sit above all valid lanes
        // and the tail chunk's carry is never consumed.

        // constant-coefficient Kogge-Stone scan: one shuffle + one FMA per step
        float bi = b;
        { float bu = __shfl_up(bi, 1);  bi = fmaf(lane >= 1  ? R1  : 0.f, bu, bi); }
        { float bu = __shfl_up(bi, 2);  bi = fmaf(lane >= 2  ? R2  : 0.f, bu, bi); }
        { float bu = __shfl_up(bi, 4);  bi = fmaf(lane >= 4  ? R4  : 0.f, bu, bi); }
        { float bu = __shfl_up(bi, 8);  bi = fmaf(lane >= 8  ? R8  : 0.f, bu, bi); }
        { float bu = __shfl_up(bi, 16); bi = fmaf(lane >= 16 ? R16 : 0.f, bu, bi); }
        { float bu = __shfl_up(bi, 32); bi = fmaf(lane >= 32 ? R32 : 0.f, bu, bi); }

        // exclusive prefix + carry
        float be = __shfl_up(bi, 1);
        if (lane == 0) be = 0.0f;
        float s = fmaf(powl, s_prev, be);

        const float b63 = __shfl(bi, 63);
        s_prev = fmaf(A256, s_prev, b63);

        // replay 4 elems, epilogue, coalesced nontemporal store (pure
        // streaming output — keep it out of L2/L3)
        if (valid) {
            f32x4 o;
            if (c == 0 && lane == 0) s = vc.x;
            else                     s = fmaf(ALPHA, s, OMA * vc.x);
            o.x = pcen_elem(vc.x, s);
            s = fmaf(ALPHA, s, OMA * vc.y);
            o.y = pcen_elem(vc.y, s);
            s = fmaf(ALPHA, s, OMA * vc.z);
            o.z = pcen_elem(vc.z, s);
            s = fmaf(ALPHA, s, OMA * vc.w);
            o.w = pcen_elem(vc.w, s);
            __builtin_nontemporal_store(o, reinterpret_cast<f32x4*>(orow + t0));
        }
    }
}

extern "C" void kernel_launch(void* const* d_in, const int* in_sizes, int n_in,
                              void* d_out, int out_size, void* d_ws, size_t ws_size,
                              hipStream_t stream) {
    const float* x = (const float*)d_in[0];
    float* out = (float*)d_out;
    const int nrows = in_sizes[0] / T_LEN;     // 4096
    const int grid = (nrows + 3) / 4;          // 4 rows (4 waves, 256 thr) per block
    pcen_kernel<<<grid, 256, 0, stream>>>(x, out, nrows);
}